// Round 1
// baseline (524.958 us; speedup 1.0000x reference)
//
#include <hip/hip_runtime.h>
#include <cstdint>
#include <cstddef>

// VAE forward, fused bf16-MFMA pipeline.
// Sizes fixed by the problem: B=32768, INPUT=1024, HIDDEN=1024, LATENT=128.
//
// Pipeline (all on `stream`, graph-capture safe):
//   1. cast x fp32->bf16 (exact: x is 0/1)
//   2. transpose-convert all weights to bf16 [N][K] ("BT" layout)
//   3. GEMM1: h = relu(x @ We1 + be1)            -> bf16 [B][1024]
//   4. GEMM2: S2 = h @ [Wmu|Wls] + [bmu|bls]     -> fp32 [B][256]
//   5. zkl:   z = mu + exp(ls)*eps (bf16), out[b] = -kl[b]
//   6. GEMM3: hd = relu(z @ Wd1 + bd1)           -> bf16 [B][1024] (reuses h buf)
//   7. GEMM4: logits = hd @ Wd2 + bd2; epilogue computes
//             -softplus(x ? -l : l) summed per row, atomicAdd into out.
//
// GEMM structure = verified m97 recipe: 128x128 block tile, BK=32, 256 thr
// (4 waves, each a 64x64 quadrant of 4x4 16x16x32 bf16 MFMA tiles),
// global_load_lds width=16 staging, ds_read_b128 fragment loads.
// Fragment layouts (HW-verified per guide):
//   A: lane holds A[m=lane&15][k=(lane>>4)*8+j], j=0..7  (BT rows likewise)
//   C: col=lane&15, row=(lane>>4)*4+reg

typedef __bf16 bf16x8 __attribute__((ext_vector_type(8)));
typedef float f32x4 __attribute__((ext_vector_type(4)));

__device__ __forceinline__ unsigned short f32_to_bf16(float f) {
  unsigned int u = __float_as_uint(f);
  u += 0x7fffu + ((u >> 16) & 1u);   // round-to-nearest-even (finite values)
  return (unsigned short)(u >> 16);
}

// ---------------- fp32 -> bf16 cast (n divisible by 4) ----------------
__global__ void cast_bf16_k(const float* __restrict__ in,
                            unsigned short* __restrict__ out, int n4) {
  int stride = gridDim.x * blockDim.x;
  for (int i = blockIdx.x * blockDim.x + threadIdx.x; i < n4; i += stride) {
    float4 v = reinterpret_cast<const float4*>(in)[i];
    ushort4 o = make_ushort4(f32_to_bf16(v.x), f32_to_bf16(v.y),
                             f32_to_bf16(v.z), f32_to_bf16(v.w));
    reinterpret_cast<ushort4*>(out)[i] = o;
  }
}

// ------------- transpose-convert: in fp32 [K][N] -> out bf16 [N][K] -------------
__global__ void transpose_bf16_k(const float* __restrict__ in,
                                 unsigned short* __restrict__ out, int K, int N) {
  __shared__ float tile[32][33];
  int n0 = blockIdx.x * 32, k0 = blockIdx.y * 32;
  int tx = threadIdx.x, ty = threadIdx.y;  // block is 32x8
#pragma unroll
  for (int r = 0; r < 32; r += 8)
    tile[ty + r][tx] = in[(size_t)(k0 + ty + r) * N + n0 + tx];
  __syncthreads();
#pragma unroll
  for (int r = 0; r < 32; r += 8)
    out[(size_t)(n0 + ty + r) * K + k0 + tx] = f32_to_bf16(tile[tx][ty + r]);
}

// async global->LDS, 16B per lane; LDS dest must be contiguous in lane order
__device__ __forceinline__ void gl_lds16(const unsigned short* g, unsigned short* l) {
  __builtin_amdgcn_global_load_lds(
      (__attribute__((address_space(1))) void*)g,
      (__attribute__((address_space(3))) void*)l, 16, 0, 0);
}

// ---------------- GEMM: C[M][N] = A[M][K] @ BT[N][K]^T + bias, fused epilogue ----------------
// EPI 0: relu -> bf16 store to outb
// EPI 1: fp32 store to outf; bias = col<128 ? bias0[col] : bias1[col-128]
// EPI 2: bernoulli LL: t = x? -l : l ; rowsum(-softplus(t)) atomicAdd into outf
template <int EPI>
__global__ __launch_bounds__(256) void gemm_bt(
    const unsigned short* __restrict__ A, const unsigned short* __restrict__ BT,
    int M, int N, int K,
    const float* __restrict__ bias0, const float* __restrict__ bias1,
    unsigned short* __restrict__ outb, float* __restrict__ outf,
    const unsigned short* __restrict__ xbf) {
  __shared__ __align__(16) unsigned short As[128 * 32];
  __shared__ __align__(16) unsigned short Bs[128 * 32];

  const int tid = threadIdx.x;
  const int lane = tid & 63;
  const int wave = tid >> 6;
  const int wr = wave >> 1, wc = wave & 1;   // 64x64 quadrant of the 128x128 tile
  const int m0 = blockIdx.y * 128;
  const int n0 = blockIdx.x * 128;
  const int lm = lane & 15, lq = lane >> 4;

  f32x4 acc[4][4] = {};

  for (int kt = 0; kt < K; kt += 32) {
    // stage A-tile (128x32) and BT-tile (128x32), 16B/lane, 2 rounds each
#pragma unroll
    for (int r = 0; r < 2; ++r) {
      int c = r * 256 + tid;        // 16B chunk id; 4 chunks per 32-elem row
      int row = c >> 2, q = c & 3;
      gl_lds16(A + (size_t)(m0 + row) * K + kt + q * 8, As + c * 8);
      gl_lds16(BT + (size_t)(n0 + row) * K + kt + q * 8, Bs + c * 8);
    }
    __syncthreads();

    bf16x8 af[4], bfr[4];
#pragma unroll
    for (int i = 0; i < 4; ++i)
      af[i] = *reinterpret_cast<const bf16x8*>(As + (wr * 64 + i * 16 + lm) * 32 + lq * 8);
#pragma unroll
    for (int j = 0; j < 4; ++j)
      bfr[j] = *reinterpret_cast<const bf16x8*>(Bs + (wc * 64 + j * 16 + lm) * 32 + lq * 8);
#pragma unroll
    for (int i = 0; i < 4; ++i)
#pragma unroll
      for (int j = 0; j < 4; ++j)
        acc[i][j] = __builtin_amdgcn_mfma_f32_16x16x32_bf16(af[i], bfr[j], acc[i][j], 0, 0, 0);
    __syncthreads();
  }

  if (EPI == 0) {
#pragma unroll
    for (int i = 0; i < 4; ++i)
#pragma unroll
      for (int j = 0; j < 4; ++j) {
        int col = n0 + wc * 64 + j * 16 + lm;
        float bias = bias0[col];
#pragma unroll
        for (int r = 0; r < 4; ++r) {
          int row = m0 + wr * 64 + i * 16 + lq * 4 + r;
          float v = acc[i][j][r] + bias;
          v = fmaxf(v, 0.f);
          outb[(size_t)row * N + col] = f32_to_bf16(v);
        }
      }
  } else if (EPI == 1) {
#pragma unroll
    for (int i = 0; i < 4; ++i)
#pragma unroll
      for (int j = 0; j < 4; ++j) {
        int col = n0 + wc * 64 + j * 16 + lm;
        float bias = (col < 128) ? bias0[col] : bias1[col - 128];
#pragma unroll
        for (int r = 0; r < 4; ++r) {
          int row = m0 + wr * 64 + i * 16 + lq * 4 + r;
          outf[(size_t)row * N + col] = acc[i][j][r] + bias;
        }
      }
  } else {
#pragma unroll
    for (int i = 0; i < 4; ++i) {
      float rs[4] = {0.f, 0.f, 0.f, 0.f};
#pragma unroll
      for (int j = 0; j < 4; ++j) {
        int col = n0 + wc * 64 + j * 16 + lm;
        float bias = bias0[col];
#pragma unroll
        for (int r = 0; r < 4; ++r) {
          int row = m0 + wr * 64 + i * 16 + lq * 4 + r;
          float l = acc[i][j][r] + bias;
          unsigned short xb = xbf[(size_t)row * N + col];  // 0x0000 or 0x3F80
          float t = xb ? -l : l;
          // -log-likelihood term: softplus(t) = max(t,0) + log1p(exp(-|t|))
          float sp = fmaxf(t, 0.f) + __logf(1.f + __expf(-fabsf(t)));
          rs[r] -= sp;
        }
      }
      // reduce over the 16 lanes sharing the same row set
#pragma unroll
      for (int off = 1; off < 16; off <<= 1)
#pragma unroll
        for (int r = 0; r < 4; ++r) rs[r] += __shfl_xor(rs[r], off, 64);
      if (lm == 0) {
#pragma unroll
        for (int r = 0; r < 4; ++r)
          atomicAdd(&outf[m0 + wr * 64 + i * 16 + lq * 4 + r], rs[r]);
      }
    }
  }
}

// ------- z = mu + exp(ls)*eps (bf16); out[b] = -kl[b] -------
__global__ void zkl_k(const float* __restrict__ S2, const float* __restrict__ eps,
                      unsigned short* __restrict__ z, float* __restrict__ out) {
  int b = blockIdx.x;
  int t = threadIdx.x;  // 128 threads, one per latent dim
  float mu = S2[(size_t)b * 256 + t];
  float ls = S2[(size_t)b * 256 + 128 + t];
  float zz = fmaf(__expf(ls), eps[(size_t)b * 128 + t], mu);
  z[(size_t)b * 128 + t] = f32_to_bf16(zz);
  float kt = 0.5f * (__expf(2.f * ls) + mu * mu - 2.f * ls - 1.f);
#pragma unroll
  for (int off = 32; off > 0; off >>= 1) kt += __shfl_down(kt, off, 64);
  __shared__ float red[2];
  if ((t & 63) == 0) red[t >> 6] = kt;
  __syncthreads();
  if (t == 0) out[b] = -(red[0] + red[1]);
}

extern "C" void kernel_launch(void* const* d_in, const int* in_sizes, int n_in,
                              void* d_out, int out_size, void* d_ws, size_t ws_size,
                              hipStream_t stream) {
  const float* x   = (const float*)d_in[0];
  const float* eps = (const float*)d_in[1];
  const float* We1 = (const float*)d_in[2];
  const float* be1 = (const float*)d_in[3];
  const float* Wmu = (const float*)d_in[4];
  const float* bmu = (const float*)d_in[5];
  const float* Wls = (const float*)d_in[6];
  const float* bls = (const float*)d_in[7];
  const float* Wd1 = (const float*)d_in[8];
  const float* bd1 = (const float*)d_in[9];
  const float* Wd2 = (const float*)d_in[10];
  const float* bd2 = (const float*)d_in[11];
  float* out = (float*)d_out;

  const int B = 32768, D = 1024, H = 1024, L = 128;

  char* ws = (char*)d_ws;
  size_t off = 0;
  auto alloc = [&](size_t bytes) {
    void* p = ws + off;
    off += (bytes + 255) & ~(size_t)255;
    return p;
  };
  unsigned short* xbf  = (unsigned short*)alloc((size_t)B * D * 2);   // 64 MB
  unsigned short* w1t  = (unsigned short*)alloc((size_t)H * D * 2);   // 2 MB  [H][D]
  unsigned short* w2t  = (unsigned short*)alloc((size_t)256 * H * 2); // 0.5MB [256][H]
  unsigned short* wd1t = (unsigned short*)alloc((size_t)H * L * 2);   // .25MB [H][L]
  unsigned short* wd2t = (unsigned short*)alloc((size_t)D * H * 2);   // 2 MB  [D][H]
  unsigned short* h    = (unsigned short*)alloc((size_t)B * H * 2);   // 64 MB
  float*          S2   = (float*)alloc((size_t)B * 256 * 4);          // 32 MB
  unsigned short* z    = (unsigned short*)alloc((size_t)B * L * 2);   // 8 MB
  unsigned short* hd   = h;  // h is dead after GEMM2 -> reuse

  dim3 tb(32, 8);
  cast_bf16_k<<<2048, 256, 0, stream>>>(x, xbf, B * D / 4);
  transpose_bf16_k<<<dim3(H / 32, D / 32), tb, 0, stream>>>(We1, w1t, D, H);
  transpose_bf16_k<<<dim3(L / 32, H / 32), tb, 0, stream>>>(Wmu, w2t, H, L);
  transpose_bf16_k<<<dim3(L / 32, H / 32), tb, 0, stream>>>(Wls, w2t + 128 * H, H, L);
  transpose_bf16_k<<<dim3(H / 32, L / 32), tb, 0, stream>>>(Wd1, wd1t, L, H);
  transpose_bf16_k<<<dim3(D / 32, H / 32), tb, 0, stream>>>(Wd2, wd2t, H, D);

  // GEMM1: h = relu(x @ We1 + be1)
  gemm_bt<0><<<dim3(H / 128, B / 128), 256, 0, stream>>>(
      xbf, w1t, B, H, D, be1, nullptr, h, nullptr, nullptr);
  // GEMM2: S2 = h @ [Wmu|Wls] + [bmu|bls]
  gemm_bt<1><<<dim3(256 / 128, B / 128), 256, 0, stream>>>(
      h, w2t, B, 256, H, bmu, bls, nullptr, S2, nullptr);
  // z, kl, out init
  zkl_k<<<B, 128, 0, stream>>>(S2, eps, z, out);
  // GEMM3: hd = relu(z @ Wd1 + bd1)
  gemm_bt<0><<<dim3(H / 128, B / 128), 256, 0, stream>>>(
      z, wd1t, B, H, L, bd1, nullptr, hd, nullptr, nullptr);
  // GEMM4: bernoulli log-likelihood accumulated into out
  gemm_bt<2><<<dim3(D / 128, B / 128), 256, 0, stream>>>(
      hd, wd2t, B, D, H, bd2, nullptr, nullptr, out, xbf);

  (void)in_sizes; (void)n_in; (void)out_size; (void)ws_size;
}

// Round 2
// 517.868 us; speedup vs baseline: 1.0137x; 1.0137x over previous
//
#include <hip/hip_runtime.h>
#include <cstdint>
#include <cstddef>

// VAE forward, fused bf16-MFMA pipeline.
// Sizes fixed by the problem: B=32768, INPUT=1024, HIDDEN=1024, LATENT=128.
//
// R2: XOR-swizzled LDS layout for the GEMM fragment reads.
//   R1 counters showed SQ_LDS_BANK_CONFLICT = 8.4M/dispatch on the big GEMMs
//   (~4 extra cyc per ds_read_b128): row stride 64B = 16 banks meant each
//   quarter-wave piled 8-way onto 4 banks. global_load_lds pins the LDS dest
//   to lane order, but the GLOBAL source is per-lane free, so we permute which
//   k-chunk each lane fetches: LDS slot s of row r holds global chunk
//   s ^ ((r>>1)&3). Read side: fragment (row, lq) sits at slot lq ^ ((lm>>1)&3).
//   Lanes then spread 2-way across all 32 banks (2-way = free, m136).
// Also: zkl reworked to one row per wave (8192x256 grid, shfl-only reduce).

typedef __bf16 bf16x8 __attribute__((ext_vector_type(8)));
typedef float f32x4 __attribute__((ext_vector_type(4)));

__device__ __forceinline__ unsigned short f32_to_bf16(float f) {
  unsigned int u = __float_as_uint(f);
  u += 0x7fffu + ((u >> 16) & 1u);   // round-to-nearest-even (finite values)
  return (unsigned short)(u >> 16);
}

// ---------------- fp32 -> bf16 cast (n divisible by 4) ----------------
__global__ void cast_bf16_k(const float* __restrict__ in,
                            unsigned short* __restrict__ out, int n4) {
  int stride = gridDim.x * blockDim.x;
  for (int i = blockIdx.x * blockDim.x + threadIdx.x; i < n4; i += stride) {
    float4 v = reinterpret_cast<const float4*>(in)[i];
    ushort4 o = make_ushort4(f32_to_bf16(v.x), f32_to_bf16(v.y),
                             f32_to_bf16(v.z), f32_to_bf16(v.w));
    reinterpret_cast<ushort4*>(out)[i] = o;
  }
}

// ------------- transpose-convert: in fp32 [K][N] -> out bf16 [N][K] -------------
__global__ void transpose_bf16_k(const float* __restrict__ in,
                                 unsigned short* __restrict__ out, int K, int N) {
  __shared__ float tile[32][33];
  int n0 = blockIdx.x * 32, k0 = blockIdx.y * 32;
  int tx = threadIdx.x, ty = threadIdx.y;  // block is 32x8
#pragma unroll
  for (int r = 0; r < 32; r += 8)
    tile[ty + r][tx] = in[(size_t)(k0 + ty + r) * N + n0 + tx];
  __syncthreads();
#pragma unroll
  for (int r = 0; r < 32; r += 8)
    out[(size_t)(n0 + ty + r) * K + k0 + tx] = f32_to_bf16(tile[tx][ty + r]);
}

// async global->LDS, 16B per lane; LDS dest must be contiguous in lane order
__device__ __forceinline__ void gl_lds16(const unsigned short* g, unsigned short* l) {
  __builtin_amdgcn_global_load_lds(
      (__attribute__((address_space(1))) void*)g,
      (__attribute__((address_space(3))) void*)l, 16, 0, 0);
}

// ---------------- GEMM: C[M][N] = A[M][K] @ BT[N][K]^T + bias, fused epilogue ----------------
// EPI 0: relu -> bf16 store to outb
// EPI 1: fp32 store to outf; bias = col<128 ? bias0[col] : bias1[col-128]
// EPI 2: bernoulli LL: t = x? -l : l ; rowsum(-softplus(t)) atomicAdd into outf
template <int EPI>
__global__ __launch_bounds__(256) void gemm_bt(
    const unsigned short* __restrict__ A, const unsigned short* __restrict__ BT,
    int M, int N, int K,
    const float* __restrict__ bias0, const float* __restrict__ bias1,
    unsigned short* __restrict__ outb, float* __restrict__ outf,
    const unsigned short* __restrict__ xbf) {
  __shared__ __align__(16) unsigned short As[128 * 32];
  __shared__ __align__(16) unsigned short Bs[128 * 32];

  const int tid = threadIdx.x;
  const int lane = tid & 63;
  const int wave = tid >> 6;
  const int wr = wave >> 1, wc = wave & 1;   // 64x64 quadrant of the 128x128 tile
  const int m0 = blockIdx.y * 128;
  const int n0 = blockIdx.x * 128;
  const int lm = lane & 15, lq = lane >> 4;

  // staging: LDS slot (c&3) of row (c>>2) receives global chunk s ^ ((row>>1)&3)
  const int c0 = tid;              // chunk ids tid and tid+256
  const int row0 = c0 >> 2, q0 = (c0 & 3) ^ ((row0 >> 1) & 3);
  const int c1 = 256 + tid;
  const int row1 = c1 >> 2, q1 = (c1 & 3) ^ ((row1 >> 1) & 3);
  const unsigned short* agp0 = A + (size_t)(m0 + row0) * K + q0 * 8;
  const unsigned short* agp1 = A + (size_t)(m0 + row1) * K + q1 * 8;
  const unsigned short* bgp0 = BT + (size_t)(n0 + row0) * K + q0 * 8;
  const unsigned short* bgp1 = BT + (size_t)(n0 + row1) * K + q1 * 8;

  // read-side swizzle: fragment chunk lq lives at slot lq ^ sw
  const int sw = (lm >> 1) & 3;
  const int aslot = (lq ^ sw) * 8;

  f32x4 acc[4][4] = {};

  for (int kt = 0; kt < K; kt += 32) {
    gl_lds16(agp0 + kt, As + c0 * 8);
    gl_lds16(agp1 + kt, As + c1 * 8);
    gl_lds16(bgp0 + kt, Bs + c0 * 8);
    gl_lds16(bgp1 + kt, Bs + c1 * 8);
    __syncthreads();

    bf16x8 af[4], bfr[4];
#pragma unroll
    for (int i = 0; i < 4; ++i)
      af[i] = *reinterpret_cast<const bf16x8*>(As + (wr * 64 + i * 16 + lm) * 32 + aslot);
#pragma unroll
    for (int j = 0; j < 4; ++j)
      bfr[j] = *reinterpret_cast<const bf16x8*>(Bs + (wc * 64 + j * 16 + lm) * 32 + aslot);
#pragma unroll
    for (int i = 0; i < 4; ++i)
#pragma unroll
      for (int j = 0; j < 4; ++j)
        acc[i][j] = __builtin_amdgcn_mfma_f32_16x16x32_bf16(af[i], bfr[j], acc[i][j], 0, 0, 0);
    __syncthreads();
  }

  if (EPI == 0) {
#pragma unroll
    for (int i = 0; i < 4; ++i)
#pragma unroll
      for (int j = 0; j < 4; ++j) {
        int col = n0 + wc * 64 + j * 16 + lm;
        float bias = bias0[col];
#pragma unroll
        for (int r = 0; r < 4; ++r) {
          int row = m0 + wr * 64 + i * 16 + lq * 4 + r;
          float v = acc[i][j][r] + bias;
          v = fmaxf(v, 0.f);
          outb[(size_t)row * N + col] = f32_to_bf16(v);
        }
      }
  } else if (EPI == 1) {
#pragma unroll
    for (int i = 0; i < 4; ++i)
#pragma unroll
      for (int j = 0; j < 4; ++j) {
        int col = n0 + wc * 64 + j * 16 + lm;
        float bias = (col < 128) ? bias0[col] : bias1[col - 128];
#pragma unroll
        for (int r = 0; r < 4; ++r) {
          int row = m0 + wr * 64 + i * 16 + lq * 4 + r;
          outf[(size_t)row * N + col] = acc[i][j][r] + bias;
        }
      }
  } else {
#pragma unroll
    for (int i = 0; i < 4; ++i) {
      float rs[4] = {0.f, 0.f, 0.f, 0.f};
#pragma unroll
      for (int j = 0; j < 4; ++j) {
        int col = n0 + wc * 64 + j * 16 + lm;
        float bias = bias0[col];
#pragma unroll
        for (int r = 0; r < 4; ++r) {
          int row = m0 + wr * 64 + i * 16 + lq * 4 + r;
          float l = acc[i][j][r] + bias;
          unsigned short xb = xbf[(size_t)row * N + col];  // 0x0000 or 0x3F80
          float t = xb ? -l : l;
          // -log-likelihood term: softplus(t) = max(t,0) + log1p(exp(-|t|))
          float sp = fmaxf(t, 0.f) + __logf(1.f + __expf(-fabsf(t)));
          rs[r] -= sp;
        }
      }
      // reduce over the 16 lanes sharing the same row set
#pragma unroll
      for (int off = 1; off < 16; off <<= 1)
#pragma unroll
        for (int r = 0; r < 4; ++r) rs[r] += __shfl_xor(rs[r], off, 64);
      if (lm == 0) {
#pragma unroll
        for (int r = 0; r < 4; ++r)
          atomicAdd(&outf[m0 + wr * 64 + i * 16 + lq * 4 + r], rs[r]);
      }
    }
  }
}

// ------- z = mu + exp(ls)*eps (bf16); out[b] = -kl[b].  One row per wave. -------
__global__ __launch_bounds__(256) void zkl_k(const float* __restrict__ S2,
                                             const float* __restrict__ eps,
                                             unsigned short* __restrict__ z,
                                             float* __restrict__ out) {
  int wave = threadIdx.x >> 6, lane = threadIdx.x & 63;
  int b = blockIdx.x * 4 + wave;
  // lane handles latent dims 2*lane, 2*lane+1 (float2/ushort2 vectorized)
  float2 mu = reinterpret_cast<const float2*>(S2 + (size_t)b * 256)[lane];
  float2 ls = reinterpret_cast<const float2*>(S2 + (size_t)b * 256 + 128)[lane];
  float2 ep = reinterpret_cast<const float2*>(eps + (size_t)b * 128)[lane];
  float z0 = fmaf(__expf(ls.x), ep.x, mu.x);
  float z1 = fmaf(__expf(ls.y), ep.y, mu.y);
  reinterpret_cast<ushort2*>(z + (size_t)b * 128)[lane] =
      make_ushort2(f32_to_bf16(z0), f32_to_bf16(z1));
  float kt = 0.5f * (__expf(2.f * ls.x) + mu.x * mu.x - 2.f * ls.x - 1.f) +
             0.5f * (__expf(2.f * ls.y) + mu.y * mu.y - 2.f * ls.y - 1.f);
#pragma unroll
  for (int off = 32; off > 0; off >>= 1) kt += __shfl_down(kt, off, 64);
  if (lane == 0) out[b] = -kt;
}

extern "C" void kernel_launch(void* const* d_in, const int* in_sizes, int n_in,
                              void* d_out, int out_size, void* d_ws, size_t ws_size,
                              hipStream_t stream) {
  const float* x   = (const float*)d_in[0];
  const float* eps = (const float*)d_in[1];
  const float* We1 = (const float*)d_in[2];
  const float* be1 = (const float*)d_in[3];
  const float* Wmu = (const float*)d_in[4];
  const float* bmu = (const float*)d_in[5];
  const float* Wls = (const float*)d_in[6];
  const float* bls = (const float*)d_in[7];
  const float* Wd1 = (const float*)d_in[8];
  const float* bd1 = (const float*)d_in[9];
  const float* Wd2 = (const float*)d_in[10];
  const float* bd2 = (const float*)d_in[11];
  float* out = (float*)d_out;

  const int B = 32768, D = 1024, H = 1024, L = 128;

  char* ws = (char*)d_ws;
  size_t off = 0;
  auto alloc = [&](size_t bytes) {
    void* p = ws + off;
    off += (bytes + 255) & ~(size_t)255;
    return p;
  };
  unsigned short* xbf  = (unsigned short*)alloc((size_t)B * D * 2);   // 64 MB
  unsigned short* w1t  = (unsigned short*)alloc((size_t)H * D * 2);   // 2 MB  [H][D]
  unsigned short* w2t  = (unsigned short*)alloc((size_t)256 * H * 2); // 0.5MB [256][H]
  unsigned short* wd1t = (unsigned short*)alloc((size_t)H * L * 2);   // .25MB [H][L]
  unsigned short* wd2t = (unsigned short*)alloc((size_t)D * H * 2);   // 2 MB  [D][H]
  unsigned short* h    = (unsigned short*)alloc((size_t)B * H * 2);   // 64 MB
  float*          S2   = (float*)alloc((size_t)B * 256 * 4);          // 32 MB
  unsigned short* z    = (unsigned short*)alloc((size_t)B * L * 2);   // 8 MB
  unsigned short* hd   = h;  // h is dead after GEMM2 -> reuse

  dim3 tb(32, 8);
  cast_bf16_k<<<2048, 256, 0, stream>>>(x, xbf, B * D / 4);
  transpose_bf16_k<<<dim3(H / 32, D / 32), tb, 0, stream>>>(We1, w1t, D, H);
  transpose_bf16_k<<<dim3(L / 32, H / 32), tb, 0, stream>>>(Wmu, w2t, H, L);
  transpose_bf16_k<<<dim3(L / 32, H / 32), tb, 0, stream>>>(Wls, w2t + 128 * H, H, L);
  transpose_bf16_k<<<dim3(H / 32, L / 32), tb, 0, stream>>>(Wd1, wd1t, L, H);
  transpose_bf16_k<<<dim3(D / 32, H / 32), tb, 0, stream>>>(Wd2, wd2t, H, D);

  // GEMM1: h = relu(x @ We1 + be1)
  gemm_bt<0><<<dim3(H / 128, B / 128), 256, 0, stream>>>(
      xbf, w1t, B, H, D, be1, nullptr, h, nullptr, nullptr);
  // GEMM2: S2 = h @ [Wmu|Wls] + [bmu|bls]
  gemm_bt<1><<<dim3(256 / 128, B / 128), 256, 0, stream>>>(
      h, w2t, B, 256, H, bmu, bls, nullptr, S2, nullptr);
  // z, kl, out init
  zkl_k<<<B / 4, 256, 0, stream>>>(S2, eps, z, out);
  // GEMM3: hd = relu(z @ Wd1 + bd1)
  gemm_bt<0><<<dim3(H / 128, B / 128), 256, 0, stream>>>(
      z, wd1t, B, H, L, bd1, nullptr, hd, nullptr, nullptr);
  // GEMM4: bernoulli log-likelihood accumulated into out
  gemm_bt<2><<<dim3(D / 128, B / 128), 256, 0, stream>>>(
      hd, wd2t, B, D, H, bd2, nullptr, nullptr, out, xbf);

  (void)in_sizes; (void)n_in; (void)out_size; (void)ws_size;
}

// Round 3
// 482.989 us; speedup vs baseline: 1.0869x; 1.0722x over previous
//
#include <hip/hip_runtime.h>
#include <cstdint>
#include <cstddef>

// VAE forward, fused bf16-MFMA pipeline.
// Sizes fixed by the problem: B=32768, INPUT=1024, HIDDEN=1024, LATENT=128.
//
// R3: XCD-pinned block swizzle for all GEMMs.
//   R2 counters: FETCH_SIZE=298MB/dispatch vs ~85MB ideal. Old grid (col,row)
//   put the 8 col-blocks sharing one A row-block on 8 DIFFERENT XCDs (linear%8
//   = col%8), so every XCD streamed the whole A matrix through its private L2.
//   New 1D grid decodes: xcd=bid&7, col=(bid>>3)%gx, row=xcd+8*((bid>>3)/gx)
//   -> all col-blocks of a row on ONE XCD, back-to-back; B (2MB) stays L2-
//   resident per XCD; A fetched once device-wide. Staging vmcnt drains become
//   L2-latency instead of L3/HBM-latency.
// R2 (kept): XOR-swizzled LDS staging (bank conflicts 8.4M -> 0).
// Also R3: five transpose launches fused into one kernel.

typedef __bf16 bf16x8 __attribute__((ext_vector_type(8)));
typedef float f32x4 __attribute__((ext_vector_type(4)));

__device__ __forceinline__ unsigned short f32_to_bf16(float f) {
  unsigned int u = __float_as_uint(f);
  u += 0x7fffu + ((u >> 16) & 1u);   // round-to-nearest-even (finite values)
  return (unsigned short)(u >> 16);
}

// ---------------- fp32 -> bf16 cast (n divisible by 4) ----------------
__global__ void cast_bf16_k(const float* __restrict__ in,
                            unsigned short* __restrict__ out, int n4) {
  int stride = gridDim.x * blockDim.x;
  for (int i = blockIdx.x * blockDim.x + threadIdx.x; i < n4; i += stride) {
    float4 v = reinterpret_cast<const float4*>(in)[i];
    ushort4 o = make_ushort4(f32_to_bf16(v.x), f32_to_bf16(v.y),
                             f32_to_bf16(v.z), f32_to_bf16(v.w));
    reinterpret_cast<ushort4*>(out)[i] = o;
  }
}

// ------------- fused transpose-convert: 5 jobs, fp32 [K][N] -> bf16 [N][K] -------------
struct TransJob { const float* in; unsigned short* out; int K, N, blkEnd; };

__global__ void transpose_all_k(TransJob j0, TransJob j1, TransJob j2,
                                TransJob j3, TransJob j4) {
  __shared__ float tile[32][33];
  int bid = blockIdx.x;
  TransJob j; int base;
  if (bid < j0.blkEnd)      { j = j0; base = 0; }
  else if (bid < j1.blkEnd) { j = j1; base = j0.blkEnd; }
  else if (bid < j2.blkEnd) { j = j2; base = j1.blkEnd; }
  else if (bid < j3.blkEnd) { j = j3; base = j2.blkEnd; }
  else                      { j = j4; base = j3.blkEnd; }
  int local = bid - base;
  int gxN = j.N >> 5;
  int n0 = (local % gxN) * 32, k0 = (local / gxN) * 32;
  int tx = threadIdx.x, ty = threadIdx.y;  // block is 32x8
#pragma unroll
  for (int r = 0; r < 32; r += 8)
    tile[ty + r][tx] = j.in[(size_t)(k0 + ty + r) * j.N + n0 + tx];
  __syncthreads();
#pragma unroll
  for (int r = 0; r < 32; r += 8)
    j.out[(size_t)(n0 + ty + r) * j.K + k0 + tx] = f32_to_bf16(tile[tx][ty + r]);
}

// async global->LDS, 16B per lane; LDS dest must be contiguous in lane order
__device__ __forceinline__ void gl_lds16(const unsigned short* g, unsigned short* l) {
  __builtin_amdgcn_global_load_lds(
      (__attribute__((address_space(1))) void*)g,
      (__attribute__((address_space(3))) void*)l, 16, 0, 0);
}

// ---------------- GEMM: C[M][N] = A[M][K] @ BT[N][K]^T + bias, fused epilogue ----------------
// 1D grid of gx*gy blocks; XCD-pinned decode (gy must be divisible by 8).
// EPI 0: relu -> bf16 store to outb
// EPI 1: fp32 store to outf; bias = col<128 ? bias0[col] : bias1[col-128]
// EPI 2: bernoulli LL: t = x? -l : l ; rowsum(-softplus(t)) atomicAdd into outf
template <int EPI>
__global__ __launch_bounds__(256) void gemm_bt(
    const unsigned short* __restrict__ A, const unsigned short* __restrict__ BT,
    int gx, int N, int K,
    const float* __restrict__ bias0, const float* __restrict__ bias1,
    unsigned short* __restrict__ outb, float* __restrict__ outf,
    const unsigned short* __restrict__ xbf) {
  __shared__ __align__(16) unsigned short As[128 * 32];
  __shared__ __align__(16) unsigned short Bs[128 * 32];

  const int tid = threadIdx.x;
  const int lane = tid & 63;
  const int wave = tid >> 6;
  const int wr = wave >> 1, wc = wave & 1;   // 64x64 quadrant of the 128x128 tile
  // XCD-pinned decode: same row-block -> same XCD, cols consecutive within it
  const int bid = blockIdx.x;
  const int xcd = bid & 7;
  const int t8 = bid >> 3;
  const int m0 = (xcd + 8 * (t8 / gx)) * 128;
  const int n0 = (t8 % gx) * 128;
  const int lm = lane & 15, lq = lane >> 4;

  // staging: LDS slot (c&3) of row (c>>2) receives global chunk (c&3)^((row>>1)&3)
  const int c0 = tid;              // chunk ids tid and tid+256
  const int row0 = c0 >> 2, q0 = (c0 & 3) ^ ((row0 >> 1) & 3);
  const int c1 = 256 + tid;
  const int row1 = c1 >> 2, q1 = (c1 & 3) ^ ((row1 >> 1) & 3);
  const unsigned short* agp0 = A + (size_t)(m0 + row0) * K + q0 * 8;
  const unsigned short* agp1 = A + (size_t)(m0 + row1) * K + q1 * 8;
  const unsigned short* bgp0 = BT + (size_t)(n0 + row0) * K + q0 * 8;
  const unsigned short* bgp1 = BT + (size_t)(n0 + row1) * K + q1 * 8;

  // read-side swizzle: fragment chunk lq lives at slot lq ^ ((lm>>1)&3)
  const int aslot = (lq ^ ((lm >> 1) & 3)) * 8;

  f32x4 acc[4][4] = {};

  for (int kt = 0; kt < K; kt += 32) {
    gl_lds16(agp0 + kt, As + c0 * 8);
    gl_lds16(agp1 + kt, As + c1 * 8);
    gl_lds16(bgp0 + kt, Bs + c0 * 8);
    gl_lds16(bgp1 + kt, Bs + c1 * 8);
    __syncthreads();

    bf16x8 af[4], bfr[4];
#pragma unroll
    for (int i = 0; i < 4; ++i)
      af[i] = *reinterpret_cast<const bf16x8*>(As + (wr * 64 + i * 16 + lm) * 32 + aslot);
#pragma unroll
    for (int j = 0; j < 4; ++j)
      bfr[j] = *reinterpret_cast<const bf16x8*>(Bs + (wc * 64 + j * 16 + lm) * 32 + aslot);
#pragma unroll
    for (int i = 0; i < 4; ++i)
#pragma unroll
      for (int j = 0; j < 4; ++j)
        acc[i][j] = __builtin_amdgcn_mfma_f32_16x16x32_bf16(af[i], bfr[j], acc[i][j], 0, 0, 0);
    __syncthreads();
  }

  if (EPI == 0) {
#pragma unroll
    for (int i = 0; i < 4; ++i)
#pragma unroll
      for (int j = 0; j < 4; ++j) {
        int col = n0 + wc * 64 + j * 16 + lm;
        float bias = bias0[col];
#pragma unroll
        for (int r = 0; r < 4; ++r) {
          int row = m0 + wr * 64 + i * 16 + lq * 4 + r;
          float v = acc[i][j][r] + bias;
          v = fmaxf(v, 0.f);
          outb[(size_t)row * N + col] = f32_to_bf16(v);
        }
      }
  } else if (EPI == 1) {
#pragma unroll
    for (int i = 0; i < 4; ++i)
#pragma unroll
      for (int j = 0; j < 4; ++j) {
        int col = n0 + wc * 64 + j * 16 + lm;
        float bias = (col < 128) ? bias0[col] : bias1[col - 128];
#pragma unroll
        for (int r = 0; r < 4; ++r) {
          int row = m0 + wr * 64 + i * 16 + lq * 4 + r;
          outf[(size_t)row * N + col] = acc[i][j][r] + bias;
        }
      }
  } else {
#pragma unroll
    for (int i = 0; i < 4; ++i) {
      float rs[4] = {0.f, 0.f, 0.f, 0.f};
#pragma unroll
      for (int j = 0; j < 4; ++j) {
        int col = n0 + wc * 64 + j * 16 + lm;
        float bias = bias0[col];
#pragma unroll
        for (int r = 0; r < 4; ++r) {
          int row = m0 + wr * 64 + i * 16 + lq * 4 + r;
          float l = acc[i][j][r] + bias;
          unsigned short xb = xbf[(size_t)row * N + col];  // 0x0000 or 0x3F80
          float t = xb ? -l : l;
          // -log-likelihood term: softplus(t) = max(t,0) + log1p(exp(-|t|))
          float sp = fmaxf(t, 0.f) + __logf(1.f + __expf(-fabsf(t)));
          rs[r] -= sp;
        }
      }
      // reduce over the 16 lanes sharing the same row set
#pragma unroll
      for (int off = 1; off < 16; off <<= 1)
#pragma unroll
        for (int r = 0; r < 4; ++r) rs[r] += __shfl_xor(rs[r], off, 64);
      if (lm == 0) {
#pragma unroll
        for (int r = 0; r < 4; ++r)
          atomicAdd(&outf[m0 + wr * 64 + i * 16 + lq * 4 + r], rs[r]);
      }
    }
  }
}

// ------- z = mu + exp(ls)*eps (bf16); out[b] = -kl[b].  One row per wave. -------
__global__ __launch_bounds__(256) void zkl_k(const float* __restrict__ S2,
                                             const float* __restrict__ eps,
                                             unsigned short* __restrict__ z,
                                             float* __restrict__ out) {
  int wave = threadIdx.x >> 6, lane = threadIdx.x & 63;
  int b = blockIdx.x * 4 + wave;
  // lane handles latent dims 2*lane, 2*lane+1 (float2/ushort2 vectorized)
  float2 mu = reinterpret_cast<const float2*>(S2 + (size_t)b * 256)[lane];
  float2 ls = reinterpret_cast<const float2*>(S2 + (size_t)b * 256 + 128)[lane];
  float2 ep = reinterpret_cast<const float2*>(eps + (size_t)b * 128)[lane];
  float z0 = fmaf(__expf(ls.x), ep.x, mu.x);
  float z1 = fmaf(__expf(ls.y), ep.y, mu.y);
  reinterpret_cast<ushort2*>(z + (size_t)b * 128)[lane] =
      make_ushort2(f32_to_bf16(z0), f32_to_bf16(z1));
  float kt = 0.5f * (__expf(2.f * ls.x) + mu.x * mu.x - 2.f * ls.x - 1.f) +
             0.5f * (__expf(2.f * ls.y) + mu.y * mu.y - 2.f * ls.y - 1.f);
#pragma unroll
  for (int off = 32; off > 0; off >>= 1) kt += __shfl_down(kt, off, 64);
  if (lane == 0) out[b] = -kt;
}

extern "C" void kernel_launch(void* const* d_in, const int* in_sizes, int n_in,
                              void* d_out, int out_size, void* d_ws, size_t ws_size,
                              hipStream_t stream) {
  const float* x   = (const float*)d_in[0];
  const float* eps = (const float*)d_in[1];
  const float* We1 = (const float*)d_in[2];
  const float* be1 = (const float*)d_in[3];
  const float* Wmu = (const float*)d_in[4];
  const float* bmu = (const float*)d_in[5];
  const float* Wls = (const float*)d_in[6];
  const float* bls = (const float*)d_in[7];
  const float* Wd1 = (const float*)d_in[8];
  const float* bd1 = (const float*)d_in[9];
  const float* Wd2 = (const float*)d_in[10];
  const float* bd2 = (const float*)d_in[11];
  float* out = (float*)d_out;

  const int B = 32768, D = 1024, H = 1024, L = 128;

  char* ws = (char*)d_ws;
  size_t off = 0;
  auto alloc = [&](size_t bytes) {
    void* p = ws + off;
    off += (bytes + 255) & ~(size_t)255;
    return p;
  };
  unsigned short* xbf  = (unsigned short*)alloc((size_t)B * D * 2);   // 64 MB
  unsigned short* w1t  = (unsigned short*)alloc((size_t)H * D * 2);   // 2 MB  [H][D]
  unsigned short* w2t  = (unsigned short*)alloc((size_t)256 * H * 2); // 0.5MB [256][H]
  unsigned short* wd1t = (unsigned short*)alloc((size_t)H * L * 2);   // .25MB [H][L]
  unsigned short* wd2t = (unsigned short*)alloc((size_t)D * H * 2);   // 2 MB  [D][H]
  unsigned short* h    = (unsigned short*)alloc((size_t)B * H * 2);   // 64 MB
  float*          S2   = (float*)alloc((size_t)B * 256 * 4);          // 32 MB
  unsigned short* z    = (unsigned short*)alloc((size_t)B * L * 2);   // 8 MB
  unsigned short* hd   = h;  // h is dead after GEMM2 -> reuse

  cast_bf16_k<<<2048, 256, 0, stream>>>(x, xbf, B * D / 4);

  // fused transposes: block ranges [0,1024) We1, [1024,1152) Wmu,
  // [1152,1280) Wls, [1280,1408) Wd1, [1408,2432) Wd2
  TransJob j0{We1, w1t, D, H, 1024};
  TransJob j1{Wmu, w2t, H, L, 1152};
  TransJob j2{Wls, w2t + 128 * H, H, L, 1280};
  TransJob j3{Wd1, wd1t, L, H, 1408};
  TransJob j4{Wd2, wd2t, H, D, 2432};
  transpose_all_k<<<2432, dim3(32, 8), 0, stream>>>(j0, j1, j2, j3, j4);

  // GEMM1: h = relu(x @ We1 + be1)        grid gx=8, gy=256
  gemm_bt<0><<<8 * 256, 256, 0, stream>>>(
      xbf, w1t, 8, H, D, be1, nullptr, h, nullptr, nullptr);
  // GEMM2: S2 = h @ [Wmu|Wls] + [bmu|bls] grid gx=2, gy=256
  gemm_bt<1><<<2 * 256, 256, 0, stream>>>(
      h, w2t, 2, 256, H, bmu, bls, nullptr, S2, nullptr);
  // z, kl, out init
  zkl_k<<<B / 4, 256, 0, stream>>>(S2, eps, z, out);
  // GEMM3: hd = relu(z @ Wd1 + bd1)       grid gx=8, gy=256
  gemm_bt<0><<<8 * 256, 256, 0, stream>>>(
      z, wd1t, 8, H, L, bd1, nullptr, hd, nullptr, nullptr);
  // GEMM4: bernoulli log-likelihood accumulated into out
  gemm_bt<2><<<8 * 256, 256, 0, stream>>>(
      hd, wd2t, 8, D, H, bd2, nullptr, nullptr, out, xbf);

  (void)in_sizes; (void)n_in; (void)out_size; (void)ws_size;
}

// Round 4
// 469.052 us; speedup vs baseline: 1.1192x; 1.0297x over previous
//
#include <hip/hip_runtime.h>
#include <cstdint>
#include <cstddef>

// VAE forward, fused bf16-MFMA pipeline.
// Sizes fixed: B=32768, INPUT=1024, HIDDEN=1024, LATENT=128.
//
// R4: (a) BK=64 K-loop for gemm_bt (16 iters instead of 32 -> half the
//     vmcnt(0)+barrier drains; 32KB LDS still allows 4+ blocks/CU).
//     New LDS swizzle for 8 chunks/row: slot = chunk ^ (row&7); per-b128
//     phase 16 lanes spread 2-way over all 32 banks (free).
//     (b) GEMM2 + zkl fused into gemm2_zkl: 128x256 tile, each wave owns
//     32 rows x 256 cols so mu (n-tile j) and ls (n-tile j+8) are in the
//     same lane; z + kl computed in-register. Removes S2 (80MB traffic),
//     one launch, and the separate zkl kernel.
// R3 (kept): XCD-pinned 1D grid decode (FETCH 298->90MB).
// R2 (kept): XOR-swizzled staging (LDS bank conflicts -> 0).

typedef __bf16 bf16x8 __attribute__((ext_vector_type(8)));
typedef float f32x4 __attribute__((ext_vector_type(4)));

__device__ __forceinline__ unsigned short f32_to_bf16(float f) {
  unsigned int u = __float_as_uint(f);
  u += 0x7fffu + ((u >> 16) & 1u);   // round-to-nearest-even (finite values)
  return (unsigned short)(u >> 16);
}

// ---------------- fp32 -> bf16 cast (n divisible by 4) ----------------
__global__ void cast_bf16_k(const float* __restrict__ in,
                            unsigned short* __restrict__ out, int n4) {
  int stride = gridDim.x * blockDim.x;
  for (int i = blockIdx.x * blockDim.x + threadIdx.x; i < n4; i += stride) {
    float4 v = reinterpret_cast<const float4*>(in)[i];
    ushort4 o = make_ushort4(f32_to_bf16(v.x), f32_to_bf16(v.y),
                             f32_to_bf16(v.z), f32_to_bf16(v.w));
    reinterpret_cast<ushort4*>(out)[i] = o;
  }
}

// ------------- fused transpose-convert: 5 jobs, fp32 [K][N] -> bf16 [N][K] -------------
struct TransJob { const float* in; unsigned short* out; int K, N, blkEnd; };

__global__ void transpose_all_k(TransJob j0, TransJob j1, TransJob j2,
                                TransJob j3, TransJob j4) {
  __shared__ float tile[32][33];
  int bid = blockIdx.x;
  TransJob j; int base;
  if (bid < j0.blkEnd)      { j = j0; base = 0; }
  else if (bid < j1.blkEnd) { j = j1; base = j0.blkEnd; }
  else if (bid < j2.blkEnd) { j = j2; base = j1.blkEnd; }
  else if (bid < j3.blkEnd) { j = j3; base = j2.blkEnd; }
  else                      { j = j4; base = j3.blkEnd; }
  int local = bid - base;
  int gxN = j.N >> 5;
  int n0 = (local % gxN) * 32, k0 = (local / gxN) * 32;
  int tx = threadIdx.x, ty = threadIdx.y;  // block is 32x8
#pragma unroll
  for (int r = 0; r < 32; r += 8)
    tile[ty + r][tx] = j.in[(size_t)(k0 + ty + r) * j.N + n0 + tx];
  __syncthreads();
#pragma unroll
  for (int r = 0; r < 32; r += 8)
    j.out[(size_t)(n0 + ty + r) * j.K + k0 + tx] = f32_to_bf16(tile[tx][ty + r]);
}

// async global->LDS, 16B per lane; LDS dest must be contiguous in lane order
__device__ __forceinline__ void gl_lds16(const unsigned short* g, unsigned short* l) {
  __builtin_amdgcn_global_load_lds(
      (__attribute__((address_space(1))) void*)g,
      (__attribute__((address_space(3))) void*)l, 16, 0, 0);
}

// ---------------- GEMM: C = A[M][K] @ BT[N][K]^T + bias, 128x128 tile, BK=64 ----------------
// 1D grid, XCD-pinned decode. EPI 0: relu->bf16. EPI 2: bernoulli LL rowsum atomicAdd.
template <int EPI>
__global__ __launch_bounds__(256) void gemm_bt(
    const unsigned short* __restrict__ A, const unsigned short* __restrict__ BT,
    int gx, int N, int K,
    const float* __restrict__ bias0,
    unsigned short* __restrict__ outb, float* __restrict__ outf,
    const unsigned short* __restrict__ xbf) {
  __shared__ __align__(16) unsigned short As[128 * 64];   // 16 KB
  __shared__ __align__(16) unsigned short Bs[128 * 64];   // 16 KB

  const int tid = threadIdx.x;
  const int lane = tid & 63;
  const int wave = tid >> 6;
  const int wr = wave >> 1, wc = wave & 1;   // 64x64 quadrant
  const int bid = blockIdx.x;
  const int xcd = bid & 7;
  const int t8 = bid >> 3;
  const int m0 = (xcd + 8 * (t8 / gx)) * 128;
  const int n0 = (t8 % gx) * 128;
  const int lm = lane & 15, lq = lane >> 4;

  // staging: 1024 16B-chunks per tile -> 4 per thread; chunk c: row=c>>3,
  // LDS slot c&7 holds global chunk (c&7)^(row&7)
  const unsigned short* agp[4];
  const unsigned short* bgp[4];
#pragma unroll
  for (int r = 0; r < 4; ++r) {
    int c = tid + 256 * r;
    int row = c >> 3, q = (c & 7) ^ (row & 7);
    agp[r] = A + (size_t)(m0 + row) * K + q * 8;
    bgp[r] = BT + (size_t)(n0 + row) * K + q * 8;
  }
  const int sw = lm & 7;   // read-side swizzle

  f32x4 acc[4][4] = {};

  for (int kt = 0; kt < K; kt += 64) {
#pragma unroll
    for (int r = 0; r < 4; ++r) {
      gl_lds16(agp[r] + kt, As + (tid + 256 * r) * 8);
      gl_lds16(bgp[r] + kt, Bs + (tid + 256 * r) * 8);
    }
    __syncthreads();

#pragma unroll
    for (int s = 0; s < 2; ++s) {
      const int so = ((s << 2) | lq) ^ sw;
      bf16x8 af[4], bfr[4];
#pragma unroll
      for (int i = 0; i < 4; ++i)
        af[i] = *reinterpret_cast<const bf16x8*>(As + (wr * 64 + i * 16 + lm) * 64 + so * 8);
#pragma unroll
      for (int j = 0; j < 4; ++j)
        bfr[j] = *reinterpret_cast<const bf16x8*>(Bs + (wc * 64 + j * 16 + lm) * 64 + so * 8);
#pragma unroll
      for (int i = 0; i < 4; ++i)
#pragma unroll
        for (int j = 0; j < 4; ++j)
          acc[i][j] = __builtin_amdgcn_mfma_f32_16x16x32_bf16(af[i], bfr[j], acc[i][j], 0, 0, 0);
    }
    __syncthreads();
  }

  if (EPI == 0) {
#pragma unroll
    for (int i = 0; i < 4; ++i)
#pragma unroll
      for (int j = 0; j < 4; ++j) {
        int col = n0 + wc * 64 + j * 16 + lm;
        float bias = bias0[col];
#pragma unroll
        for (int r = 0; r < 4; ++r) {
          int row = m0 + wr * 64 + i * 16 + lq * 4 + r;
          float v = acc[i][j][r] + bias;
          v = fmaxf(v, 0.f);
          outb[(size_t)row * N + col] = f32_to_bf16(v);
        }
      }
  } else {
#pragma unroll
    for (int i = 0; i < 4; ++i) {
      float rs[4] = {0.f, 0.f, 0.f, 0.f};
#pragma unroll
      for (int j = 0; j < 4; ++j) {
        int col = n0 + wc * 64 + j * 16 + lm;
        float bias = bias0[col];
#pragma unroll
        for (int r = 0; r < 4; ++r) {
          int row = m0 + wr * 64 + i * 16 + lq * 4 + r;
          float l = acc[i][j][r] + bias;
          unsigned short xb = xbf[(size_t)row * N + col];  // 0x0000 or 0x3F80
          float t = xb ? -l : l;
          float sp = fmaxf(t, 0.f) + __logf(1.f + __expf(-fabsf(t)));
          rs[r] -= sp;
        }
      }
#pragma unroll
      for (int off = 1; off < 16; off <<= 1)
#pragma unroll
        for (int r = 0; r < 4; ++r) rs[r] += __shfl_xor(rs[r], off, 64);
      if (lm == 0) {
#pragma unroll
        for (int r = 0; r < 4; ++r)
          atomicAdd(&outf[m0 + wr * 64 + i * 16 + lq * 4 + r], rs[r]);
      }
    }
  }
}

// -------- GEMM2+zkl fused: S2 = h @ w2t^T (N=256), z/kl in epilogue --------
// 128x256 tile per block, 4 waves each 32 rows x 256 cols; BK=64.
// acc[i][j]: mu at n-tile j (j<8), ls at j+8 -> same lane, no cross-lane.
__global__ __launch_bounds__(256, 1) void gemm2_zkl(
    const unsigned short* __restrict__ A,     // h [B][K]
    const unsigned short* __restrict__ BT,    // w2t [256][K]
    int K,
    const float* __restrict__ bmu, const float* __restrict__ bls,
    const float* __restrict__ eps,            // [B][128]
    unsigned short* __restrict__ z,           // [B][128] bf16
    float* __restrict__ out) {
  __shared__ __align__(16) unsigned short As[128 * 64];   // 16 KB
  __shared__ __align__(16) unsigned short Bs[256 * 64];   // 32 KB

  const int tid = threadIdx.x;
  const int lane = tid & 63;
  const int wave = tid >> 6;
  const int m0 = blockIdx.x * 128;
  const int lm = lane & 15, lq = lane >> 4;

  // A: 1024 chunks (4/thread); B: 2048 chunks (8/thread)
  const unsigned short* agp[4];
  const unsigned short* bgp[8];
#pragma unroll
  for (int r = 0; r < 4; ++r) {
    int c = tid + 256 * r;
    int row = c >> 3, q = (c & 7) ^ (row & 7);
    agp[r] = A + (size_t)(m0 + row) * K + q * 8;
  }
#pragma unroll
  for (int r = 0; r < 8; ++r) {
    int c = tid + 256 * r;
    int row = c >> 3, q = (c & 7) ^ (row & 7);
    bgp[r] = BT + (size_t)row * K + q * 8;
  }
  const int sw = lm & 7;

  f32x4 acc[2][16] = {};

  for (int kt = 0; kt < K; kt += 64) {
#pragma unroll
    for (int r = 0; r < 4; ++r) gl_lds16(agp[r] + kt, As + (tid + 256 * r) * 8);
#pragma unroll
    for (int r = 0; r < 8; ++r) gl_lds16(bgp[r] + kt, Bs + (tid + 256 * r) * 8);
    __syncthreads();

#pragma unroll
    for (int s = 0; s < 2; ++s) {
      const int so = ((s << 2) | lq) ^ sw;
      bf16x8 af[2];
#pragma unroll
      for (int i = 0; i < 2; ++i)
        af[i] = *reinterpret_cast<const bf16x8*>(As + (wave * 32 + i * 16 + lm) * 64 + so * 8);
#pragma unroll
      for (int j = 0; j < 16; ++j) {
        bf16x8 b = *reinterpret_cast<const bf16x8*>(Bs + (j * 16 + lm) * 64 + so * 8);
        acc[0][j] = __builtin_amdgcn_mfma_f32_16x16x32_bf16(af[0], b, acc[0][j], 0, 0, 0);
        acc[1][j] = __builtin_amdgcn_mfma_f32_16x16x32_bf16(af[1], b, acc[1][j], 0, 0, 0);
      }
    }
    __syncthreads();
  }

  // epilogue: z = mu + exp(ls)*eps, kl rowsum
#pragma unroll
  for (int i = 0; i < 2; ++i) {
    float kl[4] = {0.f, 0.f, 0.f, 0.f};
#pragma unroll
    for (int j = 0; j < 8; ++j) {
      int dim = j * 16 + lm;
      float bm = bmu[dim], bl = bls[dim];
#pragma unroll
      for (int r = 0; r < 4; ++r) {
        int row = m0 + wave * 32 + i * 16 + lq * 4 + r;
        float mu = acc[i][j][r] + bm;
        float ls = acc[i][j + 8][r] + bl;
        float e = eps[(size_t)row * 128 + dim];
        z[(size_t)row * 128 + dim] = f32_to_bf16(fmaf(__expf(ls), e, mu));
        kl[r] += 0.5f * (__expf(2.f * ls) + mu * mu - 2.f * ls - 1.f);
      }
    }
#pragma unroll
    for (int off = 1; off < 16; off <<= 1)
#pragma unroll
      for (int r = 0; r < 4; ++r) kl[r] += __shfl_xor(kl[r], off, 64);
    if (lm == 0) {
#pragma unroll
      for (int r = 0; r < 4; ++r)
        out[m0 + wave * 32 + i * 16 + lq * 4 + r] = -kl[r];
    }
  }
}

extern "C" void kernel_launch(void* const* d_in, const int* in_sizes, int n_in,
                              void* d_out, int out_size, void* d_ws, size_t ws_size,
                              hipStream_t stream) {
  const float* x   = (const float*)d_in[0];
  const float* eps = (const float*)d_in[1];
  const float* We1 = (const float*)d_in[2];
  const float* be1 = (const float*)d_in[3];
  const float* Wmu = (const float*)d_in[4];
  const float* bmu = (const float*)d_in[5];
  const float* Wls = (const float*)d_in[6];
  const float* bls = (const float*)d_in[7];
  const float* Wd1 = (const float*)d_in[8];
  const float* bd1 = (const float*)d_in[9];
  const float* Wd2 = (const float*)d_in[10];
  const float* bd2 = (const float*)d_in[11];
  float* out = (float*)d_out;

  const int B = 32768, D = 1024, H = 1024, L = 128;

  char* ws = (char*)d_ws;
  size_t off = 0;
  auto alloc = [&](size_t bytes) {
    void* p = ws + off;
    off += (bytes + 255) & ~(size_t)255;
    return p;
  };
  unsigned short* xbf  = (unsigned short*)alloc((size_t)B * D * 2);   // 64 MB
  unsigned short* w1t  = (unsigned short*)alloc((size_t)H * D * 2);   // 2 MB  [H][D]
  unsigned short* w2t  = (unsigned short*)alloc((size_t)256 * H * 2); // 0.5MB [256][H]
  unsigned short* wd1t = (unsigned short*)alloc((size_t)H * L * 2);   // .25MB [H][L]
  unsigned short* wd2t = (unsigned short*)alloc((size_t)D * H * 2);   // 2 MB  [D][H]
  unsigned short* h    = (unsigned short*)alloc((size_t)B * H * 2);   // 64 MB
  unsigned short* z    = (unsigned short*)alloc((size_t)B * L * 2);   // 8 MB
  unsigned short* hd   = h;  // h is dead after gemm2_zkl -> reuse

  cast_bf16_k<<<2048, 256, 0, stream>>>(x, xbf, B * D / 4);

  TransJob j0{We1, w1t, D, H, 1024};
  TransJob j1{Wmu, w2t, H, L, 1152};
  TransJob j2{Wls, w2t + 128 * H, H, L, 1280};
  TransJob j3{Wd1, wd1t, L, H, 1408};
  TransJob j4{Wd2, wd2t, H, D, 2432};
  transpose_all_k<<<2432, dim3(32, 8), 0, stream>>>(j0, j1, j2, j3, j4);

  // GEMM1: h = relu(x @ We1 + be1)
  gemm_bt<0><<<8 * 256, 256, 0, stream>>>(
      xbf, w1t, 8, H, D, be1, h, nullptr, nullptr);
  // GEMM2 + z/kl fused (writes z and out[b] = -kl[b])
  gemm2_zkl<<<B / 128, 256, 0, stream>>>(h, w2t, H, bmu, bls, eps, z, out);
  // GEMM3: hd = relu(z @ Wd1 + bd1)
  gemm_bt<0><<<8 * 256, 256, 0, stream>>>(
      z, wd1t, 8, H, L, bd1, hd, nullptr, nullptr);
  // GEMM4: bernoulli log-likelihood accumulated into out
  gemm_bt<2><<<8 * 256, 256, 0, stream>>>(
      hd, wd2t, 8, D, H, bd2, nullptr, out, xbf);

  (void)in_sizes; (void)n_in; (void)out_size; (void)ws_size;
}